// Round 6
// baseline (104.623 us; speedup 1.0000x reference)
//
#include <hip/hip_runtime.h>
#include <hip/hip_bf16.h>

// SpatialAttention: out[b,i,j] = softmax_j( sum_c w3[c] * tanh(x1[b,i,c] + x2[b,j,c]) )
// x1 = x@W1^T, x2 = x@W2^T.  B=4, N=1024, C=64.
//
// tanh(s) = 1 - 2/(exp2(K2*s)+1), K2 = 2*log2(e); exp2 factorizes:
// exp2(K2*(x1+x2)) = e1*e2, precomputed in proj (each clamped to 2^15).
// att = sum(w3) - 2 * sum_c w3[c] * rcp(fma(e1,e2,1)).
// Paired reciprocal over the i-pair: r = rcp(da*db); t = w3c*r;
// acc.x += db*t; acc.y += da*t   (6 full-rate + 1 trans per 2 elements).
//
// R12: R9-R11 ILP/latency fixes all null -> stall is not VMEM latency.
// Remaining invariant suspect: in-loop s_load reloads of w3q[cq] (R6
// SGPR_Count=64 proves w3 was NOT held in SGPRs -> K$-latency stalls in
// lockstep across waves; R10 regressed by ADDING uniform loads).  Fixes:
//  1. w3 staged to LDS, read per-q as ds_read_b128 -> VGPRs, no scalar stall.
//  2. 4-j blocking: thread owns {j, j+256, j+512, j+768} in ONE pass; each
//     e1/w3 ds_read feeds 16 elements (e1 reads 128->64/thread), 8 indep
//     acc chains, ch-loop removed.  __launch_bounds__(256,4) pins 128-VGPR bin.

#define BATCH 4
#define NN    1024
#define CC    64
#define TI    4              // rows i per attn block
#define BLK   256
#define PP    65             // padded pitch for transposed W in LDS
#define PROWS 16             // rows per proj block

__device__ __forceinline__ float fast_exp2(float x) {
#if __has_builtin(__builtin_amdgcn_exp2f)
    return __builtin_amdgcn_exp2f(x);
#else
    return exp2f(x);
#endif
}
__device__ __forceinline__ float fast_rcp(float x) {
#if __has_builtin(__builtin_amdgcn_rcpf)
    return __builtin_amdgcn_rcpf(x);
#else
    return 1.0f / x;
#endif
}

// ---------------- Kernel 1: projections -> exp2 factors ---------------------
// grid 256 x 512 thr; block handles rows r0..r0+15; wave w does 2 rows.
// e1p: natural [b*n][c].  e2p: c-quad-major [b][c/4][n][4] (float4 per (cq,n)).
__global__ __launch_bounds__(512) void proj_kernel(
    const float* __restrict__ x, const float* __restrict__ W1,
    const float* __restrict__ W2, float* __restrict__ e1p,
    float* __restrict__ e2p) {
    __shared__ float w1t[CC * PP];        // [c][d] transposed, 16.25 KB
    __shared__ float w2t[CC * PP];
    __shared__ float xs[PROWS * CC];      // [r][c] straight, 4 KB

    const int tid = threadIdx.x;
    const int r0  = blockIdx.x * PROWS;
    {   // W: coalesced load + transpose into LDS
        const float4* __restrict__ W1v = (const float4*)W1;
        const float4* __restrict__ W2v = (const float4*)W2;
#pragma unroll
        for (int k = 0; k < 2; ++k) {
            const int fi = k * 512 + tid;      // float4 index in [0,1024)
            const int r  = fi >> 4;            // row d
            const int c4 = (fi & 15) * 4;      // col c base
            float4 a = W1v[fi], b = W2v[fi];
            w1t[(c4 + 0) * PP + r] = a.x; w1t[(c4 + 1) * PP + r] = a.y;
            w1t[(c4 + 2) * PP + r] = a.z; w1t[(c4 + 3) * PP + r] = a.w;
            w2t[(c4 + 0) * PP + r] = b.x; w2t[(c4 + 1) * PP + r] = b.y;
            w2t[(c4 + 2) * PP + r] = b.z; w2t[(c4 + 3) * PP + r] = b.w;
        }
        // x tile: coalesced, conflict-free
        const int rr = tid >> 6, c = tid & 63;
#pragma unroll
        for (int k = 0; k < 2; ++k) {
            const int r = k * 8 + rr;
            xs[r * CC + c] = x[(size_t)(r0 + r) * CC + c];
        }
    }
    __syncthreads();

    const int w    = tid >> 6;            // 0..7
    const int lane = tid & 63;
    const int rb   = w * 2;               // this wave's 2 rows (in-block)

    float a1[2] = {0.f, 0.f};
    float a2[2] = {0.f, 0.f};
#pragma unroll
    for (int c = 0; c < CC; ++c) {
        const float w1v = w1t[c * PP + lane];
        const float w2v = w2t[c * PP + lane];
        const float x0 = xs[(rb + 0) * CC + c];   // broadcast reads
        const float x1 = xs[(rb + 1) * CC + c];
        a1[0] = fmaf(x0, w1v, a1[0]);  a2[0] = fmaf(x0, w2v, a2[0]);
        a1[1] = fmaf(x1, w1v, a1[1]);  a2[1] = fmaf(x1, w2v, a2[1]);
    }
    const float K2 = 2.8853900817779268f;  // 2*log2(e)
    // e1: natural layout (attn stages a tiny TI x C tile per block)
#pragma unroll
    for (int rr = 0; rr < 2; ++rr) {
        const size_t r = (size_t)(r0 + rb + rr);
        e1p[r * CC + lane] = fast_exp2(fminf(a1[rr] * K2, 15.f));
    }
    // e2: c-quad-major.  float addr = ((b*16 + c/4)*1024 + n)*4 + (c&3).
    {
        const int b  = r0 >> 10;          // batch of this block's rows
        const int n0 = r0 & 1023;         // row index within batch
        const int cq = lane >> 2, cm = lane & 3;
        const size_t base =
            ((((size_t)(b * 16 + cq)) << 10) + (size_t)(n0 + rb)) * 4 + cm;
#pragma unroll
        for (int rr = 0; rr < 2; ++rr) {
            e2p[base + (size_t)rr * 4] = fast_exp2(fminf(a2[rr] * K2, 15.f));
        }
    }
}

// ---------------- Kernel 2: fused att + softmax -----------------------------
// paired reciprocal for one i-pair, one j (2 elements):
__device__ __forceinline__ void step2(float e1a, float e1b, float e2,
                                      float wc, float2& acc) {
    float da = fmaf(e1a, e2, 1.f);
    float db = fmaf(e1b, e2, 1.f);
    float r  = fast_rcp(da * db);
    float t  = wc * r;
    acc.x = fmaf(db, t, acc.x);   // w3c / da
    acc.y = fmaf(da, t, acc.y);   // w3c / db
}

__global__ __launch_bounds__(BLK, 4) void attn_kernel(
    const float* __restrict__ e1p, const float* __restrict__ e2p,
    const float* __restrict__ w3, float* __restrict__ out) {
    __shared__ float e1t[CC * TI];          // [c][i] transposed: 1 KB
    __shared__ float w3s[CC];               // 256 B
    __shared__ float att_lds[TI * NN];      // 16 KB

    const int tid = threadIdx.x;            // 0..255
    const int bi  = blockIdx.x;             // 1024 blocks
    const int b   = bi >> 8;                // 256 blocks per batch
    const int i0  = (bi & 255) * TI;

    {   // stage e1 tile transposed: 256 threads cover CC*TI exactly
        const int ii = tid >> 6, c = tid & 63;
        e1t[c * TI + ii] = e1p[(size_t)((b << 10) + i0 + ii) * CC + c];
    }
    if (tid < CC) w3s[tid] = w3[tid];       // w3 -> LDS (read back as VGPRs)

    // sumw3: one-time scalar-path reduction (outside the hot loop)
    const float4* __restrict__ w3q = (const float4*)w3;
    float sumw3 = 0.f;
#pragma unroll
    for (int q = 0; q < 16; ++q) {
        float4 t = w3q[q];
        sumw3 += (t.x + t.y) + (t.z + t.w);
    }

    __syncthreads();

    const float4* e1t4 = (const float4*)e1t;   // [c] -> 4 i's (broadcast)
    const float4* w3s4 = (const float4*)w3s;   // [cq] -> 4 w3's (broadcast)
    // e2 in c-quad-major layout: float4 (cq, j) at e2b4[cq*1024 + j].
    const float4* __restrict__ e2b4 = ((const float4*)e2p) + ((size_t)b << 14);

    // acc[jj][p]: p=0 -> (i0,i1), p=1 -> (i2,i3); all indices compile-time.
    float2 acc[4][2];
#pragma unroll
    for (int jj = 0; jj < 4; ++jj) {
        acc[jj][0] = make_float2(0.f, 0.f);
        acc[jj][1] = make_float2(0.f, 0.f);
    }

#pragma unroll 1
    for (int ct = 0; ct < 4; ++ct) {               // 4 cq-tiles of 4
#pragma unroll
        for (int q = 0; q < 4; ++q) {
            const int cq = ct * 4 + q;
            float4 L[4];                           // 4 j's, coalesced 1KB/wave
#pragma unroll
            for (int jj = 0; jj < 4; ++jj)
                L[jj] = e2b4[(cq << 10) + tid + (jj << 8)];
            const float4 wv = w3s4[cq];            // ds_read_b128 -> VGPR
#pragma unroll
            for (int m = 0; m < 4; ++m) {
                const float4 ev = e1t4[cq * 4 + m]; // ds_read_b128 broadcast
                const float wc = (m == 0) ? wv.x : (m == 1) ? wv.y
                               : (m == 2) ? wv.z : wv.w;
#pragma unroll
                for (int jj = 0; jj < 4; ++jj) {
                    const float e2v = (m == 0) ? L[jj].x : (m == 1) ? L[jj].y
                                    : (m == 2) ? L[jj].z : L[jj].w;
                    step2(ev.x, ev.y, e2v, wc, acc[jj][0]);
                    step2(ev.z, ev.w, e2v, wc, acc[jj][1]);
                }
            }
        }
    }

#pragma unroll
    for (int jj = 0; jj < 4; ++jj) {
        const int j = tid + (jj << 8);
        att_lds[0 * NN + j] = fmaf(-2.f, acc[jj][0].x, sumw3);
        att_lds[1 * NN + j] = fmaf(-2.f, acc[jj][0].y, sumw3);
        att_lds[2 * NN + j] = fmaf(-2.f, acc[jj][1].x, sumw3);
        att_lds[3 * NN + j] = fmaf(-2.f, acc[jj][1].y, sumw3);
    }
    __syncthreads();

    // epilogue: wave w (0..3) softmaxes row i0+w over j — all 4 waves active
    {
        const int w    = tid >> 6;
        const int lane = tid & 63;
        float v[16];
        float m = -3.4e38f;
#pragma unroll
        for (int k = 0; k < 16; ++k) {
            v[k] = att_lds[w * NN + k * 64 + lane];
            m = fmaxf(m, v[k]);
        }
#pragma unroll
        for (int off = 32; off >= 1; off >>= 1)
            m = fmaxf(m, __shfl_xor(m, off));
        const float L2E = 1.4426950408889634f;
        float s = 0.f;
#pragma unroll
        for (int k = 0; k < 16; ++k) {
            v[k] = fast_exp2((v[k] - m) * L2E);
            s += v[k];
        }
#pragma unroll
        for (int off = 32; off >= 1; off >>= 1)
            s += __shfl_xor(s, off);
        const float rs = fast_rcp(s);
        float* __restrict__ orow = out + (((size_t)(b << 10) + (i0 + w)) << 10);
#pragma unroll
        for (int k = 0; k < 16; ++k) orow[k * 64 + lane] = v[k] * rs;
    }
}

extern "C" void kernel_launch(void* const* d_in, const int* in_sizes, int n_in,
                              void* d_out, int out_size, void* d_ws, size_t ws_size,
                              hipStream_t stream) {
    const float* x  = (const float*)d_in[0];
    const float* W1 = (const float*)d_in[1];
    const float* W2 = (const float*)d_in[2];
    const float* w3 = (const float*)d_in[3];
    float* outp = (float*)d_out;

    float* e1p = (float*)d_ws;                       // 4096*64 fp32 = 1 MB (natural)
    float* e2p = e1p + (size_t)BATCH * NN * CC;      // second 1 MB (c-quad-major)

    proj_kernel<<<dim3(BATCH * NN / PROWS), dim3(512), 0, stream>>>(x, W1, W2, e1p, e2p);
    attn_kernel<<<dim3(BATCH * NN / TI), dim3(BLK), 0, stream>>>(e1p, e2p, w3, outp);
}

// Round 7
// 98.355 us; speedup vs baseline: 1.0637x; 1.0637x over previous
//
#include <hip/hip_runtime.h>
#include <hip/hip_bf16.h>

// SpatialAttention: out[b,i,j] = softmax_j( sum_c w3[c] * tanh(x1[b,i,c] + x2[b,j,c]) )
// x1 = x@W1^T, x2 = x@W2^T.  B=4, N=1024, C=64.
//
// tanh(s) = 1 - 2/(exp2(K2*s)+1), K2 = 2*log2(e); exp2 factorizes:
// exp2(K2*(x1+x2)) = e1*e2, precomputed in proj (each clamped to 2^15).
// att = sum(w3) - 2 * sum_c w3[c] * rcp(fma(e1,e2,1)).
// Paired reciprocal over the i-pair: r = rcp(da*db); t = w3c*r;
// acc.x += db*t; acc.y += da*t   (6 full-rate + 1 trans per 2 elements).
//
// R13: R12's FETCH 17MB / WRITE 82MB (output is only 16.8MB) = scratch
// spills: launch_bounds(256,4) let the compiler pin VGPR=64 while 4-j
// blocking needs ~60+ live regs.  The 4-j idea itself targets the LDS pipe
// (R6/R9: 128 ds_read_b128/thread ~ 49K cy/CU ~ 51% of kernel; 4-j halves
// it, each e1 read feeds 16 elements).  R13 = R12 minus the spill:
//  - __launch_bounds__(256,2): VGPR cap 256, compiler allocates freely
//    (grid caps residency at 4 blocks/CU = 16 waves regardless; <=128 free).
//  - w3 back to scalar s_load path (R10 proved uniform path perf-neutral;
//    saves VGPRs + LDS reads vs R12's w3s).

#define BATCH 4
#define NN    1024
#define CC    64
#define TI    4              // rows i per attn block
#define BLK   256
#define PP    65             // padded pitch for transposed W in LDS
#define PROWS 16             // rows per proj block

__device__ __forceinline__ float fast_exp2(float x) {
#if __has_builtin(__builtin_amdgcn_exp2f)
    return __builtin_amdgcn_exp2f(x);
#else
    return exp2f(x);
#endif
}
__device__ __forceinline__ float fast_rcp(float x) {
#if __has_builtin(__builtin_amdgcn_rcpf)
    return __builtin_amdgcn_rcpf(x);
#else
    return 1.0f / x;
#endif
}

// ---------------- Kernel 1: projections -> exp2 factors ---------------------
// grid 256 x 512 thr; block handles rows r0..r0+15; wave w does 2 rows.
// e1p: natural [b*n][c].  e2p: c-quad-major [b][c/4][n][4] (float4 per (cq,n)).
__global__ __launch_bounds__(512) void proj_kernel(
    const float* __restrict__ x, const float* __restrict__ W1,
    const float* __restrict__ W2, float* __restrict__ e1p,
    float* __restrict__ e2p) {
    __shared__ float w1t[CC * PP];        // [c][d] transposed, 16.25 KB
    __shared__ float w2t[CC * PP];
    __shared__ float xs[PROWS * CC];      // [r][c] straight, 4 KB

    const int tid = threadIdx.x;
    const int r0  = blockIdx.x * PROWS;
    {   // W: coalesced load + transpose into LDS
        const float4* __restrict__ W1v = (const float4*)W1;
        const float4* __restrict__ W2v = (const float4*)W2;
#pragma unroll
        for (int k = 0; k < 2; ++k) {
            const int fi = k * 512 + tid;      // float4 index in [0,1024)
            const int r  = fi >> 4;            // row d
            const int c4 = (fi & 15) * 4;      // col c base
            float4 a = W1v[fi], b = W2v[fi];
            w1t[(c4 + 0) * PP + r] = a.x; w1t[(c4 + 1) * PP + r] = a.y;
            w1t[(c4 + 2) * PP + r] = a.z; w1t[(c4 + 3) * PP + r] = a.w;
            w2t[(c4 + 0) * PP + r] = b.x; w2t[(c4 + 1) * PP + r] = b.y;
            w2t[(c4 + 2) * PP + r] = b.z; w2t[(c4 + 3) * PP + r] = b.w;
        }
        // x tile: coalesced, conflict-free
        const int rr = tid >> 6, c = tid & 63;
#pragma unroll
        for (int k = 0; k < 2; ++k) {
            const int r = k * 8 + rr;
            xs[r * CC + c] = x[(size_t)(r0 + r) * CC + c];
        }
    }
    __syncthreads();

    const int w    = tid >> 6;            // 0..7
    const int lane = tid & 63;
    const int rb   = w * 2;               // this wave's 2 rows (in-block)

    float a1[2] = {0.f, 0.f};
    float a2[2] = {0.f, 0.f};
#pragma unroll
    for (int c = 0; c < CC; ++c) {
        const float w1v = w1t[c * PP + lane];
        const float w2v = w2t[c * PP + lane];
        const float x0 = xs[(rb + 0) * CC + c];   // broadcast reads
        const float x1 = xs[(rb + 1) * CC + c];
        a1[0] = fmaf(x0, w1v, a1[0]);  a2[0] = fmaf(x0, w2v, a2[0]);
        a1[1] = fmaf(x1, w1v, a1[1]);  a2[1] = fmaf(x1, w2v, a2[1]);
    }
    const float K2 = 2.8853900817779268f;  // 2*log2(e)
    // e1: natural layout (attn stages a tiny TI x C tile per block)
#pragma unroll
    for (int rr = 0; rr < 2; ++rr) {
        const size_t r = (size_t)(r0 + rb + rr);
        e1p[r * CC + lane] = fast_exp2(fminf(a1[rr] * K2, 15.f));
    }
    // e2: c-quad-major.  float addr = ((b*16 + c/4)*1024 + n)*4 + (c&3).
    {
        const int b  = r0 >> 10;          // batch of this block's rows
        const int n0 = r0 & 1023;         // row index within batch
        const int cq = lane >> 2, cm = lane & 3;
        const size_t base =
            ((((size_t)(b * 16 + cq)) << 10) + (size_t)(n0 + rb)) * 4 + cm;
#pragma unroll
        for (int rr = 0; rr < 2; ++rr) {
            e2p[base + (size_t)rr * 4] = fast_exp2(fminf(a2[rr] * K2, 15.f));
        }
    }
}

// ---------------- Kernel 2: fused att + softmax -----------------------------
// paired reciprocal for one i-pair, one j (2 elements):
__device__ __forceinline__ void step2(float e1a, float e1b, float e2,
                                      float wc, float2& acc) {
    float da = fmaf(e1a, e2, 1.f);
    float db = fmaf(e1b, e2, 1.f);
    float r  = fast_rcp(da * db);
    float t  = wc * r;
    acc.x = fmaf(db, t, acc.x);   // w3c / da
    acc.y = fmaf(da, t, acc.y);   // w3c / db
}

__global__ __launch_bounds__(BLK, 2) void attn_kernel(
    const float* __restrict__ e1p, const float* __restrict__ e2p,
    const float* __restrict__ w3, float* __restrict__ out) {
    __shared__ float e1t[CC * TI];          // [c][i] transposed: 1 KB
    __shared__ float att_lds[TI * NN];      // 16 KB

    const int tid = threadIdx.x;            // 0..255
    const int bi  = blockIdx.x;             // 1024 blocks
    const int b   = bi >> 8;                // 256 blocks per batch
    const int i0  = (bi & 255) * TI;

    {   // stage e1 tile transposed: 256 threads cover CC*TI exactly
        const int ii = tid >> 6, c = tid & 63;
        e1t[c * TI + ii] = e1p[(size_t)((b << 10) + i0 + ii) * CC + c];
    }

    // w3: uniform address -> scalar loads; also its sum
    const float4* __restrict__ w3q = (const float4*)w3;
    float sumw3 = 0.f;
#pragma unroll
    for (int q = 0; q < 16; ++q) {
        float4 t = w3q[q];
        sumw3 += (t.x + t.y) + (t.z + t.w);
    }

    __syncthreads();

    const float4* e1t4 = (const float4*)e1t;   // [c] -> 4 i's (broadcast)
    // e2 in c-quad-major layout: float4 (cq, j) at e2b4[cq*1024 + j].
    const float4* __restrict__ e2b4 = ((const float4*)e2p) + ((size_t)b << 14);

    // acc[jj][p]: p=0 -> (i0,i1), p=1 -> (i2,i3); all indices compile-time.
    float2 acc[4][2];
#pragma unroll
    for (int jj = 0; jj < 4; ++jj) {
        acc[jj][0] = make_float2(0.f, 0.f);
        acc[jj][1] = make_float2(0.f, 0.f);
    }

#pragma unroll 1
    for (int ct = 0; ct < 4; ++ct) {               // 4 cq-tiles of 4
#pragma unroll
        for (int q = 0; q < 4; ++q) {
            const int cq = ct * 4 + q;
            float4 L[4];                           // 4 j's, coalesced 1KB/wave
#pragma unroll
            for (int jj = 0; jj < 4; ++jj)
                L[jj] = e2b4[(cq << 10) + tid + (jj << 8)];
            const float4 wv = w3q[cq];             // s_load (uniform)
#pragma unroll
            for (int m = 0; m < 4; ++m) {
                const float4 ev = e1t4[cq * 4 + m]; // ds_read_b128 broadcast
                const float wc = (m == 0) ? wv.x : (m == 1) ? wv.y
                               : (m == 2) ? wv.z : wv.w;
#pragma unroll
                for (int jj = 0; jj < 4; ++jj) {
                    const float e2v = (m == 0) ? L[jj].x : (m == 1) ? L[jj].y
                                    : (m == 2) ? L[jj].z : L[jj].w;
                    step2(ev.x, ev.y, e2v, wc, acc[jj][0]);
                    step2(ev.z, ev.w, e2v, wc, acc[jj][1]);
                }
            }
        }
    }

#pragma unroll
    for (int jj = 0; jj < 4; ++jj) {
        const int j = tid + (jj << 8);
        att_lds[0 * NN + j] = fmaf(-2.f, acc[jj][0].x, sumw3);
        att_lds[1 * NN + j] = fmaf(-2.f, acc[jj][0].y, sumw3);
        att_lds[2 * NN + j] = fmaf(-2.f, acc[jj][1].x, sumw3);
        att_lds[3 * NN + j] = fmaf(-2.f, acc[jj][1].y, sumw3);
    }
    __syncthreads();

    // epilogue: wave w (0..3) softmaxes row i0+w over j — all 4 waves active
    {
        const int w    = tid >> 6;
        const int lane = tid & 63;
        float v[16];
        float m = -3.4e38f;
#pragma unroll
        for (int k = 0; k < 16; ++k) {
            v[k] = att_lds[w * NN + k * 64 + lane];
            m = fmaxf(m, v[k]);
        }
#pragma unroll
        for (int off = 32; off >= 1; off >>= 1)
            m = fmaxf(m, __shfl_xor(m, off));
        const float L2E = 1.4426950408889634f;
        float s = 0.f;
#pragma unroll
        for (int k = 0; k < 16; ++k) {
            v[k] = fast_exp2((v[k] - m) * L2E);
            s += v[k];
        }
#pragma unroll
        for (int off = 32; off >= 1; off >>= 1)
            s += __shfl_xor(s, off);
        const float rs = fast_rcp(s);
        float* __restrict__ orow = out + (((size_t)(b << 10) + (i0 + w)) << 10);
#pragma unroll
        for (int k = 0; k < 16; ++k) orow[k * 64 + lane] = v[k] * rs;
    }
}

extern "C" void kernel_launch(void* const* d_in, const int* in_sizes, int n_in,
                              void* d_out, int out_size, void* d_ws, size_t ws_size,
                              hipStream_t stream) {
    const float* x  = (const float*)d_in[0];
    const float* W1 = (const float*)d_in[1];
    const float* W2 = (const float*)d_in[2];
    const float* w3 = (const float*)d_in[3];
    float* outp = (float*)d_out;

    float* e1p = (float*)d_ws;                       // 4096*64 fp32 = 1 MB (natural)
    float* e2p = e1p + (size_t)BATCH * NN * CC;      // second 1 MB (c-quad-major)

    proj_kernel<<<dim3(BATCH * NN / PROWS), dim3(512), 0, stream>>>(x, W1, W2, e1p, e2p);
    attn_kernel<<<dim3(BATCH * NN / TI), dim3(BLK), 0, stream>>>(e1p, e2p, w3, outp);
}

// Round 8
// 96.725 us; speedup vs baseline: 1.0816x; 1.0168x over previous
//
#include <hip/hip_runtime.h>
#include <hip/hip_bf16.h>

// SpatialAttention: out[b,i,j] = softmax_j( sum_c w3[c] * tanh(x1[b,i,c] + x2[b,j,c]) )
// x1 = x@W1^T, x2 = x@W2^T.  B=4, N=1024, C=64.
//
// tanh(s) = 1 - 2/(exp2(K2*s)+1), K2 = 2*log2(e); exp2 factorizes:
// exp2(K2*(x1+x2)) = e1*e2, precomputed in proj (each clamped to 2^15).
// att = sum(w3) - 2 * sum_c w3[c] * rcp(fma(e1,e2,1)).
//
// R14: six structural nulls (R7/R9/R10/R11/R13) with duty pinned ~50%
// regardless of waves/CU (32 vs 16), LDS traffic (4x span), VMEM pattern,
// scalar path, prefetch depth -> limiter is per-instruction-stream ISSUE,
// not any data pipe (VALUBusy 50% x 4 SIMD ~ 2 instr/cy CU front-end).
// Fix: fewer instructions, same math.  The i-pair is a natural float2:
//   d2   = v_pk_fma_f32(e1pair, e2, 1)          ; 1 instr (was 2)
//   r    = rcp(d2.x*d2.y); t = wc*r             ; unchanged
//   acc2 = v_pk_fma_f32(d2.yx, t, acc2)         ; 1 instr (was 2), op_sel swap
// 7 issue-slots -> 5 per element-pair (-29%).  ext_vector_type(2) +
// __builtin_elementwise_fma lowers to v_pk_fma_f32 on CDNA.  Rest = R13.

#define BATCH 4
#define NN    1024
#define CC    64
#define TI    4              // rows i per attn block
#define BLK   256
#define PP    65             // padded pitch for transposed W in LDS
#define PROWS 16             // rows per proj block

typedef float v2f __attribute__((ext_vector_type(2)));

__device__ __forceinline__ float fast_exp2(float x) {
#if __has_builtin(__builtin_amdgcn_exp2f)
    return __builtin_amdgcn_exp2f(x);
#else
    return exp2f(x);
#endif
}
__device__ __forceinline__ float fast_rcp(float x) {
#if __has_builtin(__builtin_amdgcn_rcpf)
    return __builtin_amdgcn_rcpf(x);
#else
    return 1.0f / x;
#endif
}

// ---------------- Kernel 1: projections -> exp2 factors ---------------------
// grid 256 x 512 thr; block handles rows r0..r0+15; wave w does 2 rows.
// e1p: natural [b*n][c].  e2p: c-quad-major [b][c/4][n][4] (float4 per (cq,n)).
__global__ __launch_bounds__(512) void proj_kernel(
    const float* __restrict__ x, const float* __restrict__ W1,
    const float* __restrict__ W2, float* __restrict__ e1p,
    float* __restrict__ e2p) {
    __shared__ float w1t[CC * PP];        // [c][d] transposed, 16.25 KB
    __shared__ float w2t[CC * PP];
    __shared__ float xs[PROWS * CC];      // [r][c] straight, 4 KB

    const int tid = threadIdx.x;
    const int r0  = blockIdx.x * PROWS;
    {   // W: coalesced load + transpose into LDS
        const float4* __restrict__ W1v = (const float4*)W1;
        const float4* __restrict__ W2v = (const float4*)W2;
#pragma unroll
        for (int k = 0; k < 2; ++k) {
            const int fi = k * 512 + tid;      // float4 index in [0,1024)
            const int r  = fi >> 4;            // row d
            const int c4 = (fi & 15) * 4;      // col c base
            float4 a = W1v[fi], b = W2v[fi];
            w1t[(c4 + 0) * PP + r] = a.x; w1t[(c4 + 1) * PP + r] = a.y;
            w1t[(c4 + 2) * PP + r] = a.z; w1t[(c4 + 3) * PP + r] = a.w;
            w2t[(c4 + 0) * PP + r] = b.x; w2t[(c4 + 1) * PP + r] = b.y;
            w2t[(c4 + 2) * PP + r] = b.z; w2t[(c4 + 3) * PP + r] = b.w;
        }
        // x tile: coalesced, conflict-free
        const int rr = tid >> 6, c = tid & 63;
#pragma unroll
        for (int k = 0; k < 2; ++k) {
            const int r = k * 8 + rr;
            xs[r * CC + c] = x[(size_t)(r0 + r) * CC + c];
        }
    }
    __syncthreads();

    const int w    = tid >> 6;            // 0..7
    const int lane = tid & 63;
    const int rb   = w * 2;               // this wave's 2 rows (in-block)

    float a1[2] = {0.f, 0.f};
    float a2[2] = {0.f, 0.f};
#pragma unroll
    for (int c = 0; c < CC; ++c) {
        const float w1v = w1t[c * PP + lane];
        const float w2v = w2t[c * PP + lane];
        const float x0 = xs[(rb + 0) * CC + c];   // broadcast reads
        const float x1 = xs[(rb + 1) * CC + c];
        a1[0] = fmaf(x0, w1v, a1[0]);  a2[0] = fmaf(x0, w2v, a2[0]);
        a1[1] = fmaf(x1, w1v, a1[1]);  a2[1] = fmaf(x1, w2v, a2[1]);
    }
    const float K2 = 2.8853900817779268f;  // 2*log2(e)
    // e1: natural layout (attn stages a tiny TI x C tile per block)
#pragma unroll
    for (int rr = 0; rr < 2; ++rr) {
        const size_t r = (size_t)(r0 + rb + rr);
        e1p[r * CC + lane] = fast_exp2(fminf(a1[rr] * K2, 15.f));
    }
    // e2: c-quad-major.  float addr = ((b*16 + c/4)*1024 + n)*4 + (c&3).
    {
        const int b  = r0 >> 10;          // batch of this block's rows
        const int n0 = r0 & 1023;         // row index within batch
        const int cq = lane >> 2, cm = lane & 3;
        const size_t base =
            ((((size_t)(b * 16 + cq)) << 10) + (size_t)(n0 + rb)) * 4 + cm;
#pragma unroll
        for (int rr = 0; rr < 2; ++rr) {
            e2p[base + (size_t)rr * 4] = fast_exp2(fminf(a2[rr] * K2, 15.f));
        }
    }
}

// ---------------- Kernel 2: fused att + softmax -----------------------------
// packed paired reciprocal for one i-pair, one j (2 elements):
//   d2 = pk_fma(e1pair, e2, 1); r = rcp(d2.x*d2.y); t = wc*r;
//   acc2 += pk_fma(d2.yx, t)  -> acc.x += w3c/d2.x, acc.y += w3c/d2.y
__device__ __forceinline__ void step2p(v2f e1, float e2, float wc, v2f& acc) {
#if __has_builtin(__builtin_elementwise_fma)
    v2f d = __builtin_elementwise_fma(e1, (v2f){e2, e2}, (v2f){1.f, 1.f});
#else
    v2f d = e1 * (v2f){e2, e2} + (v2f){1.f, 1.f};
#endif
    const float r = fast_rcp(d.x * d.y);
    const float t = wc * r;
    const v2f sw = d.yx;                  // op_sel half-swap (free in VOP3P)
#if __has_builtin(__builtin_elementwise_fma)
    acc = __builtin_elementwise_fma(sw, (v2f){t, t}, acc);
#else
    acc = sw * (v2f){t, t} + acc;
#endif
}

__global__ __launch_bounds__(BLK, 2) void attn_kernel(
    const float* __restrict__ e1p, const float* __restrict__ e2p,
    const float* __restrict__ w3, float* __restrict__ out) {
    __shared__ float e1t[CC * TI];          // [c][i] transposed: 1 KB
    __shared__ float att_lds[TI * NN];      // 16 KB

    const int tid = threadIdx.x;            // 0..255
    const int bi  = blockIdx.x;             // 1024 blocks
    const int b   = bi >> 8;                // 256 blocks per batch
    const int i0  = (bi & 255) * TI;

    {   // stage e1 tile transposed: 256 threads cover CC*TI exactly
        const int ii = tid >> 6, c = tid & 63;
        e1t[c * TI + ii] = e1p[(size_t)((b << 10) + i0 + ii) * CC + c];
    }

    // w3: uniform address -> scalar loads; also its sum
    const float4* __restrict__ w3q = (const float4*)w3;
    float sumw3 = 0.f;
#pragma unroll
    for (int q = 0; q < 16; ++q) {
        float4 t = w3q[q];
        sumw3 += (t.x + t.y) + (t.z + t.w);
    }

    __syncthreads();

    const float4* e1t4 = (const float4*)e1t;   // [c] -> 4 i's (broadcast)
    // e2 in c-quad-major layout: float4 (cq, j) at e2b4[cq*1024 + j].
    const float4* __restrict__ e2b4 = ((const float4*)e2p) + ((size_t)b << 14);

    // acc[jj][p]: p=0 -> (i0,i1), p=1 -> (i2,i3); all indices compile-time.
    v2f acc[4][2];
#pragma unroll
    for (int jj = 0; jj < 4; ++jj) {
        acc[jj][0] = (v2f){0.f, 0.f};
        acc[jj][1] = (v2f){0.f, 0.f};
    }

#pragma unroll 1
    for (int ct = 0; ct < 4; ++ct) {               // 4 cq-tiles of 4
#pragma unroll
        for (int q = 0; q < 4; ++q) {
            const int cq = ct * 4 + q;
            float4 L[4];                           // 4 j's, coalesced 1KB/wave
#pragma unroll
            for (int jj = 0; jj < 4; ++jj)
                L[jj] = e2b4[(cq << 10) + tid + (jj << 8)];
            const float4 wv = w3q[cq];             // s_load (uniform)
#pragma unroll
            for (int m = 0; m < 4; ++m) {
                const float4 ev = e1t4[cq * 4 + m]; // ds_read_b128 broadcast
                const v2f e1lo = (v2f){ev.x, ev.y}; // i0,i1 (aligned pair)
                const v2f e1hi = (v2f){ev.z, ev.w}; // i2,i3
                const float wc = (m == 0) ? wv.x : (m == 1) ? wv.y
                               : (m == 2) ? wv.z : wv.w;
#pragma unroll
                for (int jj = 0; jj < 4; ++jj) {
                    const float e2v = (m == 0) ? L[jj].x : (m == 1) ? L[jj].y
                                    : (m == 2) ? L[jj].z : L[jj].w;
                    step2p(e1lo, e2v, wc, acc[jj][0]);
                    step2p(e1hi, e2v, wc, acc[jj][1]);
                }
            }
        }
    }

#pragma unroll
    for (int jj = 0; jj < 4; ++jj) {
        const int j = tid + (jj << 8);
        att_lds[0 * NN + j] = fmaf(-2.f, acc[jj][0].x, sumw3);
        att_lds[1 * NN + j] = fmaf(-2.f, acc[jj][0].y, sumw3);
        att_lds[2 * NN + j] = fmaf(-2.f, acc[jj][1].x, sumw3);
        att_lds[3 * NN + j] = fmaf(-2.f, acc[jj][1].y, sumw3);
    }
    __syncthreads();

    // epilogue: wave w (0..3) softmaxes row i0+w over j — all 4 waves active
    {
        const int w    = tid >> 6;
        const int lane = tid & 63;
        float v[16];
        float m = -3.4e38f;
#pragma unroll
        for (int k = 0; k < 16; ++k) {
            v[k] = att_lds[w * NN + k * 64 + lane];
            m = fmaxf(m, v[k]);
        }
#pragma unroll
        for (int off = 32; off >= 1; off >>= 1)
            m = fmaxf(m, __shfl_xor(m, off));
        const float L2E = 1.4426950408889634f;
        float s = 0.f;
#pragma unroll
        for (int k = 0; k < 16; ++k) {
            v[k] = fast_exp2((v[k] - m) * L2E);
            s += v[k];
        }
#pragma unroll
        for (int off = 32; off >= 1; off >>= 1)
            s += __shfl_xor(s, off);
        const float rs = fast_rcp(s);
        float* __restrict__ orow = out + (((size_t)(b << 10) + (i0 + w)) << 10);
#pragma unroll
        for (int k = 0; k < 16; ++k) orow[k * 64 + lane] = v[k] * rs;
    }
}

extern "C" void kernel_launch(void* const* d_in, const int* in_sizes, int n_in,
                              void* d_out, int out_size, void* d_ws, size_t ws_size,
                              hipStream_t stream) {
    const float* x  = (const float*)d_in[0];
    const float* W1 = (const float*)d_in[1];
    const float* W2 = (const float*)d_in[2];
    const float* w3 = (const float*)d_in[3];
    float* outp = (float*)d_out;

    float* e1p = (float*)d_ws;                       // 4096*64 fp32 = 1 MB (natural)
    float* e2p = e1p + (size_t)BATCH * NN * CC;      // second 1 MB (c-quad-major)

    proj_kernel<<<dim3(BATCH * NN / PROWS), dim3(512), 0, stream>>>(x, W1, W2, e1p, e2p);
    attn_kernel<<<dim3(BATCH * NN / TI), dim3(BLK), 0, stream>>>(e1p, e2p, w3, outp);
}